// Round 6
// baseline (136.000 us; speedup 1.0000x reference)
//
#include <hip/hip_runtime.h>

// ContrastiveLoss: B=16, C=256, H=32, Wd=32, K=5, SKIP=1, NEG=16
//   1) transpose z -> ztr (bf16, MFMA-fragment-major); c -> ct8 (fp8, y<30);
//      fused W fp32->bf16 fragment-major (grid z=2)
//   2) MFMA GEMM per k, fp8 output; A/B fragment loads contiguous 16B/lane
//   3) score kernel: ONE WAVE PER POSITION; 16 negative dots via
//      mfma_f32_16x16x32_fp8_fp8 (A = 16 gathered rows, B = ctx replicated 16 cols);
//      positive dot on VALU. Hinges + 2 shuffles -> per-block partial.
//   4) reduction -> d_out[0]

typedef unsigned short u16;
typedef unsigned char u8;
typedef unsigned int u32;
typedef __attribute__((ext_vector_type(8))) short bf16x8;
typedef __attribute__((ext_vector_type(4))) float f32x4;
typedef __attribute__((ext_vector_type(2))) float f32x2;

#define NEG_  16
#define MAXN_ 15360   // (32-1-1)*32*16
#define TOTROWS 71680 // sum_k (30-kidx)*512

__device__ __forceinline__ u16 f2bf(float f) {
    union { u32 i; float f; } v; v.f = f;
    u32 b = v.i;
    return (u16)((b + 0x7FFFu + ((b >> 16) & 1u)) >> 16);
}

__device__ __forceinline__ size_t frag_addr(int row, int k) {
    return ((size_t)(row >> 4) * 8 + (k >> 5)) * 512
         + (size_t)((row & 15) + 16 * ((k >> 3) & 3)) * 8 + (k & 7);
}

// ---------------- transpose + wconv ----------------
// z==0: z -> ztr (bf16 frag-major); z==1: c -> ct8 (fp8 linear, y<30); z==2: W -> Wbf (frag-major)
__global__ __launch_bounds__(256) void transpose_kernel(
    const float* __restrict__ z, const float* __restrict__ cc,
    const float* __restrict__ W,
    u16* __restrict__ ztr, u8* __restrict__ ct8, u16* __restrict__ Wbf)
{
    int tid = threadIdx.x;
    if (blockIdx.z == 2) {
        if (blockIdx.y != 0 || blockIdx.x >= 320) return;
        int i4 = blockIdx.x * 256 + tid;
        float4 v = reinterpret_cast<const float4*>(W)[i4];
        int e = i4 * 4;
        int kw = e >> 16;
        int rem = e & 65535;
        int o = rem >> 8, c = rem & 255;
        size_t base = (size_t)kw * 65536 + frag_addr(o, c);
        ushort4 u;
        u.x = f2bf(v.x); u.y = f2bf(v.y); u.z = f2bf(v.z); u.w = f2bf(v.w);
        *reinterpret_cast<ushort4*>(Wbf + base) = u;
        return;
    }
    int by = blockIdx.x;
    int b = by >> 5, y = by & 31;
    int c0 = blockIdx.y * 64;
    bool is_c = (blockIdx.z == 1);
    if (is_c && y >= 30) return;
    const float* src = is_c ? cc : z;

    __shared__ float ts[64][33];
    int x = tid & 31, ci0 = tid >> 5;
#pragma unroll
    for (int i = 0; i < 8; ++i) {
        int ci = ci0 + i * 8;
        ts[ci][x] = src[(((size_t)b * 256 + c0 + ci) * 32 + y) * 32 + x];
    }
    __syncthreads();
    int cw = tid & 63, xw0 = tid >> 6;
    if (is_c) {
#pragma unroll
        for (int i = 0; i < 8; ++i) {
            int xw = xw0 + i * 4;
            float v = ts[cw][xw];
            u32 pk = __builtin_amdgcn_cvt_pk_fp8_f32(v, v, 0, false);
            ct8[(((size_t)y * 32 + xw) * 16 + b) * 256 + c0 + cw] = (u8)pk;
        }
    } else {
        int k = c0 + cw;
#pragma unroll
        for (int i = 0; i < 8; ++i) {
            int xw = xw0 + i * 4;
            int row = (y * 32 + xw) * 16 + b;
            ztr[frag_addr(row, k)] = f2bf(ts[cw][xw]);
        }
    }
}

// ---------------- MFMA GEMM, fp8 out ----------------
__global__ __launch_bounds__(256) void gemm_mfma_kernel(
    const u16* __restrict__ ztr, const u16* __restrict__ Wbf,
    u8* __restrict__ ztwk8)
{
    int kidx = blockIdx.y;
    int rowTiles = (30 - kidx) * 8;
    if ((int)blockIdx.x >= rowTiles) return;
    int row0 = blockIdx.x * 64;
    int offk = 512 * (30 * kidx - (kidx * (kidx - 1)) / 2);

    int tile0 = (((kidx + 2) * 512 + row0) >> 4);
    const u16* Bsw = Wbf + (size_t)kidx * 65536;
    u8* out = ztwk8 + ((size_t)offk + row0) * 256;

    int wid = threadIdx.x >> 6, lane = threadIdx.x & 63;
    int col0 = wid * 64;

    f32x4 acc[4][4] = {};

    for (int kb = 0; kb < 8; ++kb) {
        bf16x8 a[4], b[4];
#pragma unroll
        for (int i = 0; i < 4; ++i)
            a[i] = *reinterpret_cast<const bf16x8*>(
                ztr + ((size_t)(tile0 + i) * 8 + kb) * 512 + lane * 8);
#pragma unroll
        for (int j = 0; j < 4; ++j)
            b[j] = *reinterpret_cast<const bf16x8*>(
                Bsw + ((size_t)(wid * 4 + j) * 8 + kb) * 512 + lane * 8);
#pragma unroll
        for (int i = 0; i < 4; ++i)
#pragma unroll
            for (int j = 0; j < 4; ++j)
                acc[i][j] = __builtin_amdgcn_mfma_f32_16x16x32_bf16(b[j], a[i], acc[i][j], 0, 0, 0);
    }

    int lr = lane & 15;
    int rq = (lane >> 4) * 4;
#pragma unroll
    for (int i = 0; i < 4; ++i) {
#pragma unroll
        for (int j = 0; j < 4; ++j) {
            u32 u = 0;
            u = __builtin_amdgcn_cvt_pk_fp8_f32(acc[i][j][0], acc[i][j][1], u, false);
            u = __builtin_amdgcn_cvt_pk_fp8_f32(acc[i][j][2], acc[i][j][3], u, true);
            *reinterpret_cast<u32*>(out + (size_t)(i * 16 + lr) * 256 + col0 + j * 16 + rq) = u;
        }
    }
}

// ---------------- scores + hinge (MFMA negatives) ----------------
// One wave per position. A-frag lane l: 8 fp8 of negative row idx[l&15] at
// k-slot (l>>4)*8; B-frag lane l: same 8 ctx bytes per quad-group (broadcast).
// D: lane l holds negatives n=(l>>4)*4+reg (replicated over l&15).
__global__ __launch_bounds__(256) void score_kernel(
    const u8* __restrict__ ztwk8, const u8* __restrict__ ct8,
    const int* __restrict__ rind, float* __restrict__ partials)
{
    __shared__ float red[4];
    int wid = threadIdx.x >> 6, lane = threadIdx.x & 63;
    int gp = blockIdx.x * 4 + wid;

    const int ends0 = 15360, ends1 = 30208, ends2 = 44544, ends3 = 58368;
    int kidx, off;
    if (gp < ends0)      { kidx = 0; off = 0; }
    else if (gp < ends1) { kidx = 1; off = ends0; }
    else if (gp < ends2) { kidx = 2; off = ends1; }
    else if (gp < ends3) { kidx = 3; off = ends2; }
    else                 { kidx = 4; off = ends3; }
    int Nk = (30 - kidx) * 512;
    int local = gp - off;

    int n16 = lane & 15, kq = lane >> 4;

    int rv = rind[(size_t)kidx * (MAXN_ * NEG_) + (size_t)local * NEG_ + n16];
    int idx = rv >= Nk ? rv - Nk : rv;

    const u8* arow = ztwk8 + ((size_t)(off + idx)) * 256 + kq * 8;
    const u8* brow = ct8 + (size_t)local * 256 + kq * 8;

    long av[8], bv[8];
#pragma unroll
    for (int kk = 0; kk < 8; ++kk) {
        av[kk] = *reinterpret_cast<const long*>(arow + kk * 32);
        bv[kk] = *reinterpret_cast<const long*>(brow + kk * 32);
    }
    // positive dot inputs (VALU path)
    u32 pw = *reinterpret_cast<const u32*>(ztwk8 + (size_t)gp * 256 + lane * 4);
    u32 cw = *reinterpret_cast<const u32*>(ct8 + (size_t)local * 256 + lane * 4);

    f32x4 acc = {};
#pragma unroll
    for (int kk = 0; kk < 8; ++kk)
        acc = __builtin_amdgcn_mfma_f32_16x16x32_fp8_fp8(av[kk], bv[kk], acc, 0, 0, 0);

    // positive
    f32x2 pl = __builtin_amdgcn_cvt_pk_f32_fp8(pw, false);
    f32x2 ph = __builtin_amdgcn_cvt_pk_f32_fp8(pw, true);
    f32x2 cl = __builtin_amdgcn_cvt_pk_f32_fp8(cw, false);
    f32x2 ch = __builtin_amdgcn_cvt_pk_f32_fp8(cw, true);
    float p = pl.x * cl.x + pl.y * cl.y + ph.x * ch.x + ph.y * ch.y;
#pragma unroll
    for (int s = 1; s < 64; s <<= 1) p += __shfl_xor(p, s);

    // negatives: hinge the 4 scores this lane holds, reduce across quad-groups
    float h = fmaxf(0.f, 1.f + acc[0]) + fmaxf(0.f, 1.f + acc[1])
            + fmaxf(0.f, 1.f + acc[2]) + fmaxf(0.f, 1.f + acc[3]);
    h += __shfl_xor(h, 16);
    h += __shfl_xor(h, 32);

    float val = (fmaxf(0.f, 1.f - p) + h * (1.0f / 16.0f)) / (float)Nk;

    if (lane == 0) red[wid] = val;
    __syncthreads();
    if (threadIdx.x == 0)
        partials[blockIdx.x] = red[0] + red[1] + red[2] + red[3];
}

__global__ __launch_bounds__(256) void reduce_kernel(
    const float* __restrict__ partials, float* __restrict__ out, int n)
{
    __shared__ float s[256];
    float a = 0.f;
    for (int i = threadIdx.x; i < n; i += 256) a += partials[i];
    s[threadIdx.x] = a;
    __syncthreads();
    for (int st = 128; st > 0; st >>= 1) {
        if ((int)threadIdx.x < st) s[threadIdx.x] += s[threadIdx.x + st];
        __syncthreads();
    }
    if (threadIdx.x == 0) out[0] = s[0];
}

extern "C" void kernel_launch(void* const* d_in, const int* in_sizes, int n_in,
                              void* d_out, int out_size, void* d_ws, size_t ws_size,
                              hipStream_t stream) {
    const float* z    = (const float*)d_in[0];
    const float* c    = (const float*)d_in[1];
    const float* W    = (const float*)d_in[2];
    const int*   rind = (const int*)d_in[3];

    char* ws = (char*)d_ws;
    u16*   ztr   = (u16*)  (ws + 0);            // 16384*256*2 = 8,388,608 (frag-major)
    u8*    ct8   = (u8*)   (ws + 8388608);      // 15360*256   = 3,932,160 (fp8)
    u8*    ztwk8 = (u8*)   (ws + 12320768);     // 71680*256   = 18,350,080
    float* parts = (float*)(ws + 30670848);     // 17920*4     = 71,680
    u16*   Wbf   = (u16*)  (ws + 30742528);     // 327680*2    = 655,360 (frag-major)
    float* out   = (float*)d_out;

    transpose_kernel<<<dim3(512, 4, 3), 256, 0, stream>>>(z, c, W, ztr, ct8, Wbf);
    gemm_mfma_kernel<<<dim3(240, 5), 256, 0, stream>>>(ztr, Wbf, ztwk8);
    score_kernel<<<dim3(TOTROWS / 4), 256, 0, stream>>>(ztwk8, ct8, rind, parts);
    reduce_kernel<<<dim3(1), 256, 0, stream>>>(parts, out, TOTROWS / 4);
}

// Round 7
// 91.046 us; speedup vs baseline: 1.4937x; 1.4937x over previous
//
#include <hip/hip_runtime.h>

// ContrastiveLoss: B=16, C=256, H=32, Wd=32, K=5, SKIP=1, NEG=16
//   1) transpose: z -> ztr (bf16 frag-major, COALESCED 1KB wave stores);
//      c -> ctf (fp32 linear, y<30); W -> Wbf (bf16 frag-major)
//   2) MFMA GEMM per k, fp8 output (swapped operands; frag loads 16B/lane contiguous)
//   3) score: wave per position (round-5 structure), fp8 gathers 256B-contiguous
//      per 16-lane group, packed-f32 FMA dots, XCD-chunked block swizzle
//   4) reduction -> d_out[0]

typedef unsigned short u16;
typedef unsigned char u8;
typedef unsigned int u32;
typedef __attribute__((ext_vector_type(8))) short bf16x8;
typedef __attribute__((ext_vector_type(4))) float f32x4;
typedef __attribute__((ext_vector_type(2))) float f32x2;

#define NEG_  16
#define MAXN_ 15360   // (32-1-1)*32*16
#define TOTROWS 71680 // sum_k (30-kidx)*512

__device__ __forceinline__ u16 f2bf(float f) {
    union { u32 i; float f; } v; v.f = f;
    u32 b = v.i;
    return (u16)((b + 0x7FFFu + ((b >> 16) & 1u)) >> 16);
}

__device__ __forceinline__ size_t frag_addr(int row, int k) {
    return ((size_t)(row >> 4) * 8 + (k >> 5)) * 512
         + (size_t)((row & 15) + 16 * ((k >> 3) & 3)) * 8 + (k & 7);
}

// ---------------- transpose + wconv ----------------
// z==0 (bx<64, by=kchunk): z -> ztr frag-major, coalesced 1KB wave stores
// z==1: c -> ctf (fp32 linear, y<30)   [round-5 proven path]
// z==2 (bx<320, by==0): W -> Wbf frag-major
__global__ __launch_bounds__(256) void transpose_kernel(
    const float* __restrict__ z, const float* __restrict__ cc,
    const float* __restrict__ W,
    u16* __restrict__ ztr, float* __restrict__ ctf, u16* __restrict__ Wbf)
{
    __shared__ float smemf[8704];           // 34816 B; aliased as u16 for z-path
    int tid = threadIdx.x;

    if (blockIdx.z == 2) {
        if (blockIdx.y != 0 || blockIdx.x >= 320) return;
        int i4 = blockIdx.x * 256 + tid;
        float4 v = reinterpret_cast<const float4*>(W)[i4];
        int e = i4 * 4;
        int kw = e >> 16;
        int rem = e & 65535;
        int o = rem >> 8, c = rem & 255;
        size_t base = (size_t)kw * 65536 + frag_addr(o, c);
        ushort4 u;
        u.x = f2bf(v.x); u.y = f2bf(v.y); u.z = f2bf(v.z); u.w = f2bf(v.w);
        *reinterpret_cast<ushort4*>(Wbf + base) = u;
        return;
    }

    if (blockIdx.z == 0) {
        // z -> ztr frag-major. Block: y = bx>>1, xg = bx&1 (16 x's), kc = by (64 chans).
        if (blockIdx.x >= 64) return;
        u16* s16 = reinterpret_cast<u16*>(smemf);   // [c(64)][b(16)][x(17 pad)]
        int y = blockIdx.x >> 1, xg = blockIdx.x & 1, kc = blockIdx.y;
        int x0 = xg * 16;

        int c0t = tid >> 2, xq = (tid & 3) * 4;     // chan-local, x-quad
#pragma unroll
        for (int bb = 0; bb < 16; ++bb) {
            float4 v = *reinterpret_cast<const float4*>(
                z + (((size_t)bb * 256 + kc * 64 + c0t) * 32 + y) * 32 + x0 + xq);
            u16* d = s16 + c0t * 272 + bb * 17 + xq;
            d[0] = f2bf(v.x); d[1] = f2bf(v.y); d[2] = f2bf(v.z); d[3] = f2bf(v.w);
        }
        __syncthreads();

        int w = tid >> 6, lane = tid & 63;
        int b = lane & 15, q = lane >> 4;
#pragma unroll
        for (int t = 0; t < 8; ++t) {
            int fb = w * 8 + t;
            int rtl = fb >> 1, kbl = fb & 1;
            int rt = y * 32 + x0 + rtl;
            ushort4 lo, hi;
            const u16* s = s16 + (kbl * 32 + q * 8) * 272 + b * 17 + rtl;
            lo.x = s[0 * 272]; lo.y = s[1 * 272]; lo.z = s[2 * 272]; lo.w = s[3 * 272];
            hi.x = s[4 * 272]; hi.y = s[5 * 272]; hi.z = s[6 * 272]; hi.w = s[7 * 272];
            u16* dst = ztr + ((size_t)rt * 8 + kc * 2 + kbl) * 512 + lane * 8;
            *reinterpret_cast<ushort4*>(dst) = lo;
            *reinterpret_cast<ushort4*>(dst + 4) = hi;
        }
        return;
    }

    // z==1: c -> ctf fp32
    int by = blockIdx.x;
    int b = by >> 5, y = by & 31;
    int c0 = blockIdx.y * 64;
    if (y >= 30) return;
    float (*ts)[33] = reinterpret_cast<float(*)[33]>(smemf);
    int x = tid & 31, ci0 = tid >> 5;
#pragma unroll
    for (int i = 0; i < 8; ++i) {
        int ci = ci0 + i * 8;
        ts[ci][x] = cc[(((size_t)b * 256 + c0 + ci) * 32 + y) * 32 + x];
    }
    __syncthreads();
    int cw = tid & 63, xw0 = tid >> 6;
#pragma unroll
    for (int i = 0; i < 8; ++i) {
        int xw = xw0 + i * 4;
        ctf[(((size_t)y * 32 + xw) * 16 + b) * 256 + c0 + cw] = ts[cw][xw];
    }
}

// ---------------- MFMA GEMM, fp8 out ----------------
__global__ __launch_bounds__(256) void gemm_mfma_kernel(
    const u16* __restrict__ ztr, const u16* __restrict__ Wbf,
    u8* __restrict__ ztwk8)
{
    int kidx = blockIdx.y;
    int rowTiles = (30 - kidx) * 8;
    if ((int)blockIdx.x >= rowTiles) return;
    int row0 = blockIdx.x * 64;
    int offk = 512 * (30 * kidx - (kidx * (kidx - 1)) / 2);

    int tile0 = (((kidx + 2) * 512 + row0) >> 4);
    const u16* Bsw = Wbf + (size_t)kidx * 65536;
    u8* out = ztwk8 + ((size_t)offk + row0) * 256;

    int wid = threadIdx.x >> 6, lane = threadIdx.x & 63;
    int col0 = wid * 64;

    f32x4 acc[4][4] = {};

    for (int kb = 0; kb < 8; ++kb) {
        bf16x8 a[4], b[4];
#pragma unroll
        for (int i = 0; i < 4; ++i)
            a[i] = *reinterpret_cast<const bf16x8*>(
                ztr + ((size_t)(tile0 + i) * 8 + kb) * 512 + lane * 8);
#pragma unroll
        for (int j = 0; j < 4; ++j)
            b[j] = *reinterpret_cast<const bf16x8*>(
                Bsw + ((size_t)(wid * 4 + j) * 8 + kb) * 512 + lane * 8);
#pragma unroll
        for (int i = 0; i < 4; ++i)
#pragma unroll
            for (int j = 0; j < 4; ++j)
                acc[i][j] = __builtin_amdgcn_mfma_f32_16x16x32_bf16(b[j], a[i], acc[i][j], 0, 0, 0);
    }

    int lr = lane & 15;
    int rq = (lane >> 4) * 4;
#pragma unroll
    for (int i = 0; i < 4; ++i) {
#pragma unroll
        for (int j = 0; j < 4; ++j) {
            u32 u = 0;
            u = __builtin_amdgcn_cvt_pk_fp8_f32(acc[i][j][0], acc[i][j][1], u, false);
            u = __builtin_amdgcn_cvt_pk_fp8_f32(acc[i][j][2], acc[i][j][3], u, true);
            *reinterpret_cast<u32*>(out + (size_t)(i * 16 + lr) * 256 + col0 + j * 16 + rq) = u;
        }
    }
}

// ---------------- scores + hinge ----------------
// dot of 16 fp8 chans vs 8 packed-f32 ctx pairs: 8 cvt_pk + 8 pk_fma
__device__ __forceinline__ float dot16(uint4 nb, const f32x2* cp) {
    f32x2 d0 = {0.f, 0.f}, d1 = {0.f, 0.f};
    d0 += __builtin_amdgcn_cvt_pk_f32_fp8(nb.x, false) * cp[0];
    d1 += __builtin_amdgcn_cvt_pk_f32_fp8(nb.x, true)  * cp[1];
    d0 += __builtin_amdgcn_cvt_pk_f32_fp8(nb.y, false) * cp[2];
    d1 += __builtin_amdgcn_cvt_pk_f32_fp8(nb.y, true)  * cp[3];
    d0 += __builtin_amdgcn_cvt_pk_f32_fp8(nb.z, false) * cp[4];
    d1 += __builtin_amdgcn_cvt_pk_f32_fp8(nb.z, true)  * cp[5];
    d0 += __builtin_amdgcn_cvt_pk_f32_fp8(nb.w, false) * cp[6];
    d1 += __builtin_amdgcn_cvt_pk_f32_fp8(nb.w, true)  * cp[7];
    f32x2 d = d0 + d1;
    return d.x + d.y;
}

// wave per position; lane = (r = neg-slot 0..3, c16 = 16B chunk 0..15).
// XCD-chunked swizzle: 17920 blocks = 8 * 2240.
__global__ __launch_bounds__(256) void score_kernel(
    const u8* __restrict__ ztwk8, const float* __restrict__ ctf,
    const int* __restrict__ rind, float* __restrict__ partials)
{
    __shared__ float red[4];
    int bid = blockIdx.x;
    int swb = (bid & 7) * 2240 + (bid >> 3);
    int wid = threadIdx.x >> 6, lane = threadIdx.x & 63;
    int gp = swb * 4 + wid;

    const int ends0 = 15360, ends1 = 30208, ends2 = 44544, ends3 = 58368;
    int kidx, off;
    if (gp < ends0)      { kidx = 0; off = 0; }
    else if (gp < ends1) { kidx = 1; off = ends0; }
    else if (gp < ends2) { kidx = 2; off = ends1; }
    else if (gp < ends3) { kidx = 3; off = ends2; }
    else                 { kidx = 4; off = ends3; }
    int Nk = (30 - kidx) * 512;
    int local = gp - off;

    int r = lane >> 4, c16 = lane & 15;

    const int* rbase = rind + (size_t)kidx * (MAXN_ * NEG_) + (size_t)local * NEG_ + r;
    int rv0 = rbase[0], rv1 = rbase[4], rv2 = rbase[8], rv3 = rbase[12];
    int i0 = rv0 >= Nk ? rv0 - Nk : rv0;
    int i1 = rv1 >= Nk ? rv1 - Nk : rv1;
    int i2 = rv2 >= Nk ? rv2 - Nk : rv2;
    int i3 = rv3 >= Nk ? rv3 - Nk : rv3;

    const u8* zb = ztwk8 + (size_t)off * 256 + c16 * 16;
    uint4 nb0 = *reinterpret_cast<const uint4*>(zb + (size_t)i0 * 256);
    uint4 nb1 = *reinterpret_cast<const uint4*>(zb + (size_t)i1 * 256);
    uint4 nb2 = *reinterpret_cast<const uint4*>(zb + (size_t)i2 * 256);
    uint4 nb3 = *reinterpret_cast<const uint4*>(zb + (size_t)i3 * 256);
    uint4 pb  = *reinterpret_cast<const uint4*>(ztwk8 + (size_t)gp * 256 + c16 * 16);

    f32x2 cp[8];
    const f32x2* cb = reinterpret_cast<const f32x2*>(ctf + (size_t)local * 256 + c16 * 16);
#pragma unroll
    for (int i = 0; i < 8; ++i) cp[i] = cb[i];

    float p = dot16(pb, cp);
    p += __shfl_xor(p, 1); p += __shfl_xor(p, 2);
    p += __shfl_xor(p, 4); p += __shfl_xor(p, 8);
    float val = (r == 0) ? fmaxf(0.f, 1.f - p) : 0.f;

    float d, h = 0.f;
    d = dot16(nb0, cp);
    d += __shfl_xor(d, 1); d += __shfl_xor(d, 2);
    d += __shfl_xor(d, 4); d += __shfl_xor(d, 8);
    h += fmaxf(0.f, 1.f + d);
    d = dot16(nb1, cp);
    d += __shfl_xor(d, 1); d += __shfl_xor(d, 2);
    d += __shfl_xor(d, 4); d += __shfl_xor(d, 8);
    h += fmaxf(0.f, 1.f + d);
    d = dot16(nb2, cp);
    d += __shfl_xor(d, 1); d += __shfl_xor(d, 2);
    d += __shfl_xor(d, 4); d += __shfl_xor(d, 8);
    h += fmaxf(0.f, 1.f + d);
    d = dot16(nb3, cp);
    d += __shfl_xor(d, 1); d += __shfl_xor(d, 2);
    d += __shfl_xor(d, 4); d += __shfl_xor(d, 8);
    h += fmaxf(0.f, 1.f + d);

    val += h * (1.0f / 16.0f);
    val += __shfl_xor(val, 16);
    val += __shfl_xor(val, 32);
    val *= 1.0f / (float)Nk;

    if (lane == 0) red[wid] = val;
    __syncthreads();
    if (threadIdx.x == 0)
        partials[bid] = red[0] + red[1] + red[2] + red[3];
}

__global__ __launch_bounds__(256) void reduce_kernel(
    const float* __restrict__ partials, float* __restrict__ out, int n)
{
    __shared__ float s[256];
    float a = 0.f;
    for (int i = threadIdx.x; i < n; i += 256) a += partials[i];
    s[threadIdx.x] = a;
    __syncthreads();
    for (int st = 128; st > 0; st >>= 1) {
        if ((int)threadIdx.x < st) s[threadIdx.x] += s[threadIdx.x + st];
        __syncthreads();
    }
    if (threadIdx.x == 0) out[0] = s[0];
}

extern "C" void kernel_launch(void* const* d_in, const int* in_sizes, int n_in,
                              void* d_out, int out_size, void* d_ws, size_t ws_size,
                              hipStream_t stream) {
    const float* z    = (const float*)d_in[0];
    const float* c    = (const float*)d_in[1];
    const float* W    = (const float*)d_in[2];
    const int*   rind = (const int*)d_in[3];

    char* ws = (char*)d_ws;
    u16*   ztr   = (u16*)  (ws + 0);            // 16384*256*2 = 8,388,608 (frag-major)
    float* ctf   = (float*)(ws + 8388608);      // 15360*256*4 = 15,728,640
    u8*    ztwk8 = (u8*)   (ws + 24117248);     // 71680*256   = 18,350,080
    float* parts = (float*)(ws + 42467328);     // 17920*4     = 71,680
    u16*   Wbf   = (u16*)  (ws + 42539008);     // 327680*2    = 655,360 (frag-major)
    float* out   = (float*)d_out;

    transpose_kernel<<<dim3(512, 4, 3), 256, 0, stream>>>(z, c, W, ztr, ctf, Wbf);
    gemm_mfma_kernel<<<dim3(240, 5), 256, 0, stream>>>(ztr, Wbf, ztwk8);
    score_kernel<<<dim3(TOTROWS / 4), 256, 0, stream>>>(ztwk8, ctf, rind, parts);
    reduce_kernel<<<dim3(1), 256, 0, stream>>>(parts, out, TOTROWS / 4);
}

// Round 8
// 71.115 us; speedup vs baseline: 1.9124x; 1.2803x over previous
//
#include <hip/hip_runtime.h>

// ContrastiveLoss: B=16, C=256, H=32, Wd=32, K=5, SKIP=1, NEG=16
//   1) transpose: z -> ztr (bf16 frag-major, r5-proven path); c -> ct8 (fp8 linear);
//      W -> Wbf (bf16 frag-major)
//   2) MFMA GEMM per k, fp8 out + FUSED positive-score hinge partial per block
//   3) score: wave per position, negatives only; fp8 ctx unpacked once; packed-f32 FMA;
//      XCD-chunked swizzle
//   4) two-stage reduction over [score partials | gemm pos partials] -> d_out[0]

typedef unsigned short u16;
typedef unsigned char u8;
typedef unsigned int u32;
typedef __attribute__((ext_vector_type(8))) short bf16x8;
typedef __attribute__((ext_vector_type(4))) float f32x4;
typedef __attribute__((ext_vector_type(2))) float f32x2;

#define NEG_  16
#define MAXN_ 15360   // (32-1-1)*32*16
#define TOTROWS 71680 // sum_k (30-kidx)*512
#define NSCORE 17920  // TOTROWS/4
#define NPOSP  1200   // 240*5 gemm blocks (invalid -> 0)
#define NPARTS (NSCORE + NPOSP)

__device__ __forceinline__ u16 f2bf(float f) {
    union { u32 i; float f; } v; v.f = f;
    u32 b = v.i;
    return (u16)((b + 0x7FFFu + ((b >> 16) & 1u)) >> 16);
}

__device__ __forceinline__ size_t frag_addr(int row, int k) {
    return ((size_t)(row >> 4) * 8 + (k >> 5)) * 512
         + (size_t)((row & 15) + 16 * ((k >> 3) & 3)) * 8 + (k & 7);
}

// ---------------- transpose + wconv ----------------
// z==0: z -> ztr (bf16 frag-major, r5 path); z==1: c -> ct8 (fp8, y<30); z==2: W -> Wbf
__global__ __launch_bounds__(256) void transpose_kernel(
    const float* __restrict__ z, const float* __restrict__ cc,
    const float* __restrict__ W,
    u16* __restrict__ ztr, u8* __restrict__ ct8, u16* __restrict__ Wbf)
{
    int tid = threadIdx.x;
    if (blockIdx.z == 2) {
        if (blockIdx.y != 0 || blockIdx.x >= 320) return;
        int i4 = blockIdx.x * 256 + tid;
        float4 v = reinterpret_cast<const float4*>(W)[i4];
        int e = i4 * 4;
        int kw = e >> 16;
        int rem = e & 65535;
        int o = rem >> 8, c = rem & 255;
        size_t base = (size_t)kw * 65536 + frag_addr(o, c);
        ushort4 u;
        u.x = f2bf(v.x); u.y = f2bf(v.y); u.z = f2bf(v.z); u.w = f2bf(v.w);
        *reinterpret_cast<ushort4*>(Wbf + base) = u;
        return;
    }
    int by = blockIdx.x;
    int b = by >> 5, y = by & 31;
    int c0 = blockIdx.y * 64;
    bool is_c = (blockIdx.z == 1);
    if (is_c && y >= 30) return;
    const float* src = is_c ? cc : z;

    __shared__ float ts[64][33];
    int x = tid & 31, ci0 = tid >> 5;
#pragma unroll
    for (int i = 0; i < 8; ++i) {
        int ci = ci0 + i * 8;
        ts[ci][x] = src[(((size_t)b * 256 + c0 + ci) * 32 + y) * 32 + x];
    }
    __syncthreads();
    int cw = tid & 63, xw0 = tid >> 6;
    if (is_c) {
#pragma unroll
        for (int i = 0; i < 8; ++i) {
            int xw = xw0 + i * 4;
            float v = ts[cw][xw];
            u32 pk = __builtin_amdgcn_cvt_pk_fp8_f32(v, v, 0, false);
            ct8[(((size_t)y * 32 + xw) * 16 + b) * 256 + c0 + cw] = (u8)pk;
        }
    } else {
        int k = c0 + cw;
#pragma unroll
        for (int i = 0; i < 8; ++i) {
            int xw = xw0 + i * 4;
            int row = (y * 32 + xw) * 16 + b;
            ztr[frag_addr(row, k)] = f2bf(ts[cw][xw]);
        }
    }
}

// ---------------- MFMA GEMM, fp8 out + fused positive ----------------
__global__ __launch_bounds__(256) void gemm_mfma_kernel(
    const u16* __restrict__ ztr, const u16* __restrict__ Wbf,
    const u8* __restrict__ ct8,
    u8* __restrict__ ztwk8, float* __restrict__ posPart)
{
    int kidx = blockIdx.y;
    int rowTiles = (30 - kidx) * 8;
    if ((int)blockIdx.x >= rowTiles) {
        if (threadIdx.x == 0) posPart[kidx * 240 + blockIdx.x] = 0.f;
        return;
    }
    int row0 = blockIdx.x * 64;
    int offk = 512 * (30 * kidx - (kidx * (kidx - 1)) / 2);

    int tile0 = (((kidx + 2) * 512 + row0) >> 4);
    const u16* Bsw = Wbf + (size_t)kidx * 65536;
    u8* out = ztwk8 + ((size_t)offk + row0) * 256;

    int wid = threadIdx.x >> 6, lane = threadIdx.x & 63;
    int col0 = wid * 64;

    f32x4 acc[4][4] = {};

    for (int kb = 0; kb < 8; ++kb) {
        bf16x8 a[4], b[4];
#pragma unroll
        for (int i = 0; i < 4; ++i)
            a[i] = *reinterpret_cast<const bf16x8*>(
                ztr + ((size_t)(tile0 + i) * 8 + kb) * 512 + lane * 8);
#pragma unroll
        for (int j = 0; j < 4; ++j)
            b[j] = *reinterpret_cast<const bf16x8*>(
                Bsw + ((size_t)(wid * 4 + j) * 8 + kb) * 512 + lane * 8);
#pragma unroll
        for (int i = 0; i < 4; ++i)
#pragma unroll
            for (int j = 0; j < 4; ++j)
                acc[i][j] = __builtin_amdgcn_mfma_f32_16x16x32_bf16(b[j], a[i], acc[i][j], 0, 0, 0);
    }

    int lr = lane & 15;
    int rq = (lane >> 4) * 4;
    __shared__ float pos[4][64];

#pragma unroll
    for (int i = 0; i < 4; ++i) {
        int local = row0 + i * 16 + lr;                 // slice-local row
        float pp = 0.f;
#pragma unroll
        for (int j = 0; j < 4; ++j) {
            // fp8 store
            u32 u = 0;
            u = __builtin_amdgcn_cvt_pk_fp8_f32(acc[i][j][0], acc[i][j][1], u, false);
            u = __builtin_amdgcn_cvt_pk_fp8_f32(acc[i][j][2], acc[i][j][3], u, true);
            *reinterpret_cast<u32*>(out + (size_t)(i * 16 + lr) * 256 + col0 + j * 16 + rq) = u;
            // positive partial vs fp8 ctx
            u32 cw_ = *reinterpret_cast<const u32*>(ct8 + (size_t)local * 256 + col0 + j * 16 + rq);
            f32x2 clo = __builtin_amdgcn_cvt_pk_f32_fp8(cw_, false);
            f32x2 chi = __builtin_amdgcn_cvt_pk_f32_fp8(cw_, true);
            pp = fmaf(acc[i][j][0], clo.x, pp);
            pp = fmaf(acc[i][j][1], clo.y, pp);
            pp = fmaf(acc[i][j][2], chi.x, pp);
            pp = fmaf(acc[i][j][3], chi.y, pp);
        }
        pp += __shfl_xor(pp, 16);
        pp += __shfl_xor(pp, 32);
        if (lane < 16) pos[wid][i * 16 + lane] = pp;
    }
    __syncthreads();

    if (threadIdx.x < 64) {
        float p = pos[0][threadIdx.x] + pos[1][threadIdx.x]
                + pos[2][threadIdx.x] + pos[3][threadIdx.x];
        float Nk = (float)((30 - kidx) * 512);
        float h = fmaxf(0.f, 1.f - p) / Nk;
#pragma unroll
        for (int s = 1; s < 64; s <<= 1) h += __shfl_xor(h, s);
        if (threadIdx.x == 0) posPart[kidx * 240 + blockIdx.x] = h;
    }
}

// ---------------- negative scores + hinge ----------------
__device__ __forceinline__ float dot16(uint4 nb, const f32x2* cp) {
    f32x2 d0 = {0.f, 0.f}, d1 = {0.f, 0.f};
    d0 += __builtin_amdgcn_cvt_pk_f32_fp8(nb.x, false) * cp[0];
    d1 += __builtin_amdgcn_cvt_pk_f32_fp8(nb.x, true)  * cp[1];
    d0 += __builtin_amdgcn_cvt_pk_f32_fp8(nb.y, false) * cp[2];
    d1 += __builtin_amdgcn_cvt_pk_f32_fp8(nb.y, true)  * cp[3];
    d0 += __builtin_amdgcn_cvt_pk_f32_fp8(nb.z, false) * cp[4];
    d1 += __builtin_amdgcn_cvt_pk_f32_fp8(nb.z, true)  * cp[5];
    d0 += __builtin_amdgcn_cvt_pk_f32_fp8(nb.w, false) * cp[6];
    d1 += __builtin_amdgcn_cvt_pk_f32_fp8(nb.w, true)  * cp[7];
    f32x2 d = d0 + d1;
    return d.x + d.y;
}

// wave per position; lane = (r = neg-slot 0..3, c16 = 16B chunk 0..15).
// XCD-chunked swizzle: 17920 blocks = 8 * 2240.
__global__ __launch_bounds__(256) void score_kernel(
    const u8* __restrict__ ztwk8, const u8* __restrict__ ct8,
    const int* __restrict__ rind, float* __restrict__ partials)
{
    __shared__ float red[4];
    int bid = blockIdx.x;
    int swb = (bid & 7) * 2240 + (bid >> 3);
    int wid = threadIdx.x >> 6, lane = threadIdx.x & 63;
    int gp = swb * 4 + wid;

    const int ends0 = 15360, ends1 = 30208, ends2 = 44544, ends3 = 58368;
    int kidx, off;
    if (gp < ends0)      { kidx = 0; off = 0; }
    else if (gp < ends1) { kidx = 1; off = ends0; }
    else if (gp < ends2) { kidx = 2; off = ends1; }
    else if (gp < ends3) { kidx = 3; off = ends2; }
    else                 { kidx = 4; off = ends3; }
    int Nk = (30 - kidx) * 512;
    int local = gp - off;

    int r = lane >> 4, c16 = lane & 15;

    const int* rbase = rind + (size_t)kidx * (MAXN_ * NEG_) + (size_t)local * NEG_ + r;
    int rv0 = rbase[0], rv1 = rbase[4], rv2 = rbase[8], rv3 = rbase[12];
    int i0 = rv0 >= Nk ? rv0 - Nk : rv0;
    int i1 = rv1 >= Nk ? rv1 - Nk : rv1;
    int i2 = rv2 >= Nk ? rv2 - Nk : rv2;
    int i3 = rv3 >= Nk ? rv3 - Nk : rv3;

    const u8* zb = ztwk8 + (size_t)off * 256 + c16 * 16;
    uint4 nb0 = *reinterpret_cast<const uint4*>(zb + (size_t)i0 * 256);
    uint4 nb1 = *reinterpret_cast<const uint4*>(zb + (size_t)i1 * 256);
    uint4 nb2 = *reinterpret_cast<const uint4*>(zb + (size_t)i2 * 256);
    uint4 nb3 = *reinterpret_cast<const uint4*>(zb + (size_t)i3 * 256);

    uint4 cw4 = *reinterpret_cast<const uint4*>(ct8 + (size_t)local * 256 + c16 * 16);
    f32x2 cp[8];
    cp[0] = __builtin_amdgcn_cvt_pk_f32_fp8(cw4.x, false);
    cp[1] = __builtin_amdgcn_cvt_pk_f32_fp8(cw4.x, true);
    cp[2] = __builtin_amdgcn_cvt_pk_f32_fp8(cw4.y, false);
    cp[3] = __builtin_amdgcn_cvt_pk_f32_fp8(cw4.y, true);
    cp[4] = __builtin_amdgcn_cvt_pk_f32_fp8(cw4.z, false);
    cp[5] = __builtin_amdgcn_cvt_pk_f32_fp8(cw4.z, true);
    cp[6] = __builtin_amdgcn_cvt_pk_f32_fp8(cw4.w, false);
    cp[7] = __builtin_amdgcn_cvt_pk_f32_fp8(cw4.w, true);

    float d, h = 0.f;
    d = dot16(nb0, cp);
    d += __shfl_xor(d, 1); d += __shfl_xor(d, 2);
    d += __shfl_xor(d, 4); d += __shfl_xor(d, 8);
    h += fmaxf(0.f, 1.f + d);
    d = dot16(nb1, cp);
    d += __shfl_xor(d, 1); d += __shfl_xor(d, 2);
    d += __shfl_xor(d, 4); d += __shfl_xor(d, 8);
    h += fmaxf(0.f, 1.f + d);
    d = dot16(nb2, cp);
    d += __shfl_xor(d, 1); d += __shfl_xor(d, 2);
    d += __shfl_xor(d, 4); d += __shfl_xor(d, 8);
    h += fmaxf(0.f, 1.f + d);
    d = dot16(nb3, cp);
    d += __shfl_xor(d, 1); d += __shfl_xor(d, 2);
    d += __shfl_xor(d, 4); d += __shfl_xor(d, 8);
    h += fmaxf(0.f, 1.f + d);

    float val = h * (1.0f / 16.0f);
    val += __shfl_xor(val, 16);
    val += __shfl_xor(val, 32);
    val *= 1.0f / (float)Nk;

    if (lane == 0) red[wid] = val;
    __syncthreads();
    if (threadIdx.x == 0)
        partials[bid] = red[0] + red[1] + red[2] + red[3];
}

// ---------------- two-stage reduction ----------------
__global__ __launch_bounds__(256) void reduce1_kernel(
    const float* __restrict__ comb, float* __restrict__ r1)
{
    __shared__ float s[256];
    float a = 0.f;
    for (int i = blockIdx.x * 256 + threadIdx.x; i < NPARTS; i += 64 * 256)
        a += comb[i];
    s[threadIdx.x] = a;
    __syncthreads();
    for (int st = 128; st > 0; st >>= 1) {
        if ((int)threadIdx.x < st) s[threadIdx.x] += s[threadIdx.x + st];
        __syncthreads();
    }
    if (threadIdx.x == 0) r1[blockIdx.x] = s[0];
}

__global__ __launch_bounds__(64) void reduce2_kernel(
    const float* __restrict__ r1, float* __restrict__ out)
{
    float a = r1[threadIdx.x];
#pragma unroll
    for (int s = 1; s < 64; s <<= 1) a += __shfl_xor(a, s);
    if (threadIdx.x == 0) out[0] = a;
}

extern "C" void kernel_launch(void* const* d_in, const int* in_sizes, int n_in,
                              void* d_out, int out_size, void* d_ws, size_t ws_size,
                              hipStream_t stream) {
    const float* z    = (const float*)d_in[0];
    const float* c    = (const float*)d_in[1];
    const float* W    = (const float*)d_in[2];
    const int*   rind = (const int*)d_in[3];

    char* ws = (char*)d_ws;
    u16*   ztr     = (u16*)  (ws + 0);            // 16384*256*2 = 8,388,608 (frag-major)
    u8*    ct8     = (u8*)   (ws + 8388608);      // 15360*256   = 3,932,160 (fp8)
    u8*    ztwk8   = (u8*)   (ws + 12320768);     // 71680*256   = 18,350,080
    float* parts   = (float*)(ws + 30670848);     // NSCORE*4    = 71,680
    float* posPart = (float*)(ws + 30742528);     // NPOSP*4     = 4,800 (contiguous after parts)
    float* r1      = (float*)(ws + 30747328);     // 64*4        = 256
    u16*   Wbf     = (u16*)  (ws + 30747648);     // 327680*2    = 655,360 (frag-major)
    float* out     = (float*)d_out;

    transpose_kernel<<<dim3(512, 4, 3), 256, 0, stream>>>(z, c, W, ztr, ct8, Wbf);
    gemm_mfma_kernel<<<dim3(240, 5), 256, 0, stream>>>(ztr, Wbf, ct8, ztwk8, posPart);
    score_kernel<<<dim3(NSCORE), 256, 0, stream>>>(ztwk8, ct8, rind, parts);
    reduce1_kernel<<<dim3(64), 256, 0, stream>>>(parts, r1);
    reduce2_kernel<<<dim3(1), 64, 0, stream>>>(r1, out);
}